// Round 9
// baseline (325.958 us; speedup 1.0000x reference)
//
#include <hip/hip_runtime.h>

#define NB 65536
typedef unsigned short ushortt;

typedef __attribute__((ext_vector_type(8))) short bf16x8;
typedef __attribute__((ext_vector_type(4))) float f32x4;

__device__ __forceinline__ unsigned cvtpk(float lo, float hi) {
  unsigned r;
  asm("v_cvt_pk_bf16_f32 %0, %1, %2" : "=v"(r) : "v"(lo), "v"(hi));
  return r;
}
__device__ __forceinline__ unsigned short f2bf(float f) {
  union { float f; unsigned u; } v; v.f = f;
  return (unsigned short)((v.u + 0x7FFFu + ((v.u >> 16) & 1u)) >> 16);
}
__device__ __forceinline__ float fast_tanh(float x) {
  float e = __builtin_amdgcn_exp2f(__builtin_fabsf(x) * -2.885390081777927f);
  float t = (1.0f - e) * __builtin_amdgcn_rcpf(1.0f + e);
  return __builtin_copysignf(t, x);
}

#define MFMA16(acc, a, b) \
  acc = __builtin_amdgcn_mfma_f32_16x16x32_bf16(a, b, acc, 0, 0, 0)

// ws layout (bf16 element offsets) — weights k-slice packed [NS][N][32]
#define OFF_W1P  0        // [8 ks][1024][32]
#define OFF_KAVP 262144   // [12 ks][256][32]  rows=[C1|D1]
#define OFF_KANP 360448   // [12 ks][256][32]  rows=[A1|B1]
#define OFF_KBSP 458752   // [8 ks][384][32]   rows=[A2;C2]
#define OFF_KBHP 557056   // [32 ks][384][32]  rows=[B2@W2 ; D2@W2]
#define WS_END   950272
#define OFF_BIAS_BYTES ((size_t)WS_END * 2)

// padded LDS strides (elems): 40*2B=80B rows -> lane-bank-uniform b128 reads
#define ALD 40
#define BLD 40

// ===================== prep: pack weights + fuse [B2;D2]@W2 =====================
struct PP {
  const float *A1, *B1, *C1, *D1, *A2, *B2, *C2, *D2, *W1, *W2, *b2;
};

__global__ void prep(PP p, unsigned short* __restrict__ wbf, float* __restrict__ bias384) {
  const int bid = blockIdx.x, t = threadIdx.x;
  if (bid < 272) {                       // pack W1P/KAVP/KANP/KBSP (8 elems/thread)
    const int e8 = (bid * 256 + t) * 8;  // 272*256*8 == 557056
    const float* src;
    if (e8 < 262144) {                   // W1P [8][1024][32]
      const int ks = e8 >> 15, row = (e8 >> 5) & 1023, kk = e8 & 31;
      src = p.W1 + (size_t)row * 256 + ks * 32 + kk;
    } else if (e8 < 360448) {            // KAVP [12][256][32]
      const int q = e8 - 262144;
      const int ks = q / 8192, n = (q / 32) % 256, kk = q % 32;
      src = (ks < 8) ? p.C1 + (size_t)n * 256 + ks * 32 + kk
                     : p.D1 + (size_t)n * 128 + (ks - 8) * 32 + kk;
    } else if (e8 < 458752) {            // KANP [12][256][32]
      const int q = e8 - 360448;
      const int ks = q / 8192, n = (q / 32) % 256, kk = q % 32;
      src = (ks < 8) ? p.A1 + (size_t)n * 256 + ks * 32 + kk
                     : p.B1 + (size_t)n * 128 + (ks - 8) * 32 + kk;
    } else {                             // KBSP [8][384][32]
      const int q = e8 - 458752;
      const int ks = q / 12288, n = (q / 32) % 384, kk = q % 32;
      src = (n < 256) ? p.A2 + (size_t)n * 256 + ks * 32 + kk
                      : p.C2 + (size_t)(n - 256) * 256 + ks * 32 + kk;
    }
    const float4 f0 = *(const float4*)src, f1 = *(const float4*)(src + 4);
    uint4 h;
    h.x = cvtpk(f0.x, f0.y); h.y = cvtpk(f0.z, f0.w);
    h.z = cvtpk(f1.x, f1.y); h.w = cvtpk(f1.z, f1.w);
    *(uint4*)(wbf + e8) = h;
  } else if (bid < 272 + 192) {          // KBHP = [B2;D2] @ W2, packed
    const int fb = bid - 272;
    const int rb8 = (fb >> 2) * 8;       // row block of 8 (never straddles 256)
    const int k = (fb & 3) * 256 + t;
    float acc[8] = {};
    for (int j = 0; j < 256; ++j) {
      const float w2v = p.W2[(size_t)j * 1024 + k];
      #pragma unroll
      for (int r = 0; r < 8; ++r) {
        const int row = rb8 + r;
        const float sv = (row < 256) ? p.B2[row * 256 + j] : p.D2[(row - 256) * 256 + j];
        acc[r] += sv * w2v;
      }
    }
    #pragma unroll
    for (int r = 0; r < 8; ++r)
      wbf[OFF_KBHP + (size_t)(k >> 5) * 12288 + (rb8 + r) * 32 + (k & 31)] = f2bf(acc[r]);
  } else {                               // bias384 = [B2;D2] @ b2
    const int r = (bid - 464) * 256 + t;
    if (r < 384) {
      const float* S = (r < 256) ? (p.B2 + r * 256) : (p.D2 + (r - 256) * 256);
      float a = 0.f;
      for (int j = 0; j < 256; ++j) a += S[j] * p.b2[j];
      bias384[r] = a;
    }
  }
}

// ========= k256: C[128,256] = [s1|u] @ Wpackᵀ (kav: bf16; kan: fp32) =========
__global__ __launch_bounds__(512, 4) void k256(
    const float* __restrict__ s1, const float* __restrict__ u,
    const unsigned short* __restrict__ wbf, int boff,
    float* __restrict__ outf, unsigned short* __restrict__ outb)
{
  __shared__ unsigned short At[2][128 * ALD];   // 10240 B each
  __shared__ unsigned short Bt[2][256 * BLD];   // 20480 B each
  const int t = threadIdx.x, wc = t >> 6, lid = t & 63;
  const int lr = lid & 15, lg = lid >> 4;
  const int wm = wc >> 2, wn = wc & 3;
  const int row0 = blockIdx.x * 128;
  const int ar = t >> 2, ac = (t & 3) * 8;   // A stage coords (128 rows x 32)

  float4 a0, a1; uint4 b0, b1;
  auto loadA = [&](int ks) {
    const float* src; int ld, c0;
    if (ks < 8) { src = s1; ld = 256; c0 = ks * 32; }
    else        { src = u;  ld = 128; c0 = ks * 32 - 256; }
    const float* q = src + (size_t)(row0 + ar) * ld + c0 + ac;
    a0 = *(const float4*)q; a1 = *(const float4*)(q + 4);
  };
  auto loadB = [&](int ks) {
    const unsigned short* s = wbf + boff + ks * 8192 + t * 8;
    b0 = *(const uint4*)s; b1 = *(const uint4*)(s + 4096);
  };
  auto writeA = [&](int buf) {
    uint4 h;
    h.x = cvtpk(a0.x, a0.y); h.y = cvtpk(a0.z, a0.w);
    h.z = cvtpk(a1.x, a1.y); h.w = cvtpk(a1.z, a1.w);
    *(uint4*)&At[buf][ar * ALD + ac] = h;
  };
  auto writeB = [&](int buf) {
    *(uint4*)&Bt[buf][ar * BLD + ac] = b0;
    *(uint4*)&Bt[buf][(ar + 128) * BLD + ac] = b1;
  };

  f32x4 acc[4][4] = {};
  loadA(0); loadB(0); writeA(0); writeB(0);
  __syncthreads();
  for (int ks = 0; ks < 12; ++ks) {
    const int cur = ks & 1;
    if (ks < 11) { loadA(ks + 1); loadB(ks + 1); }
    bf16x8 a[4];
    #pragma unroll
    for (int m = 0; m < 4; ++m)
      a[m] = *(const bf16x8*)&At[cur][(wm * 64 + m * 16 + lr) * ALD + lg * 8];
    #pragma unroll
    for (int n = 0; n < 4; ++n) {
      bf16x8 b = *(const bf16x8*)&Bt[cur][(wn * 64 + n * 16 + lr) * BLD + lg * 8];
      #pragma unroll
      for (int m = 0; m < 4; ++m) MFMA16(acc[m][n], a[m], b);
    }
    if (ks < 11) { writeA(cur ^ 1); writeB(cur ^ 1); }
    __syncthreads();
  }
  if (outf) {
    #pragma unroll
    for (int m = 0; m < 4; ++m)
      #pragma unroll
      for (int n = 0; n < 4; ++n)
        #pragma unroll
        for (int i = 0; i < 4; ++i)
          outf[(size_t)(row0 + wm * 64 + m * 16 + lg * 4 + i) * 256 + wn * 64 + n * 16 + lr] = acc[m][n][i];
  } else {
    #pragma unroll
    for (int m = 0; m < 4; ++m)
      #pragma unroll
      for (int n = 0; n < 4; ++n)
        #pragma unroll
        for (int i = 0; i < 4; ++i)
          outb[(size_t)(row0 + wm * 64 + m * 16 + lg * 4 + i) * 256 + wn * 64 + n * 16 + lr] = f2bf(acc[m][n][i]);
  }
}

// ====== kbh: h[:, nq*256..+255] = tanh(v @ W1ᵀ + b1)  (M=128, N=256) ======
__global__ __launch_bounds__(512, 4) void kbh(
    const unsigned short* __restrict__ vsrc, const unsigned short* __restrict__ wbf,
    const float* __restrict__ b1,
    unsigned short* __restrict__ h0, unsigned short* __restrict__ h1)
{
  __shared__ unsigned short At[2][128 * ALD];
  __shared__ unsigned short Bt[2][256 * BLD];
  const int t = threadIdx.x, wc = t >> 6, lid = t & 63;
  const int lr = lid & 15, lg = lid >> 4;
  const int wm = wc >> 2, wn = wc & 3;
  const int nq = blockIdx.x & 3;
  const int row0 = (blockIdx.x >> 2) * 128;
  const int ar = t >> 2, ac = (t & 3) * 8;
  unsigned short* hreg = (nq < 2) ? h0 : h1;
  const int colb = (nq & 1) * 256;

  uint4 av, b0, b1v;
  auto loadA = [&](int ks) {
    av = *(const uint4*)(vsrc + (size_t)(row0 + ar) * 256 + ks * 32 + ac);
  };
  auto loadB = [&](int ks) {
    const unsigned short* s = wbf + OFF_W1P + ks * 32768 + nq * 8192 + t * 8;
    b0 = *(const uint4*)s; b1v = *(const uint4*)(s + 4096);
  };
  auto writeA = [&](int buf) { *(uint4*)&At[buf][ar * ALD + ac] = av; };
  auto writeB = [&](int buf) {
    *(uint4*)&Bt[buf][ar * BLD + ac] = b0;
    *(uint4*)&Bt[buf][(ar + 128) * BLD + ac] = b1v;
  };

  f32x4 acc[4][4] = {};
  loadA(0); loadB(0); writeA(0); writeB(0);
  __syncthreads();
  for (int ks = 0; ks < 8; ++ks) {
    const int cur = ks & 1;
    if (ks < 7) { loadA(ks + 1); loadB(ks + 1); }
    bf16x8 a[4];
    #pragma unroll
    for (int m = 0; m < 4; ++m)
      a[m] = *(const bf16x8*)&At[cur][(wm * 64 + m * 16 + lr) * ALD + lg * 8];
    #pragma unroll
    for (int n = 0; n < 4; ++n) {
      bf16x8 b = *(const bf16x8*)&Bt[cur][(wn * 64 + n * 16 + lr) * BLD + lg * 8];
      #pragma unroll
      for (int m = 0; m < 4; ++m) MFMA16(acc[m][n], a[m], b);
    }
    if (ks < 7) { writeA(cur ^ 1); writeB(cur ^ 1); }
    __syncthreads();
  }
  // epilogue: tanh+bias, 2-phase LDS pack (hp aliases Bt) for coalesced h writes
  unsigned short* hp = &Bt[0][0];    // needs 64*260 = 16640 elems <= 20480
  #pragma unroll
  for (int p = 0; p < 2; ++p) {
    if (wm == p) {
      #pragma unroll
      for (int n = 0; n < 4; ++n) {
        const int colc = wn * 64 + n * 16 + lr;
        const float b1v_ = b1[nq * 256 + colc];
        #pragma unroll
        for (int m = 0; m < 4; ++m)
          #pragma unroll
          for (int i = 0; i < 4; ++i)
            hp[(m * 16 + lg * 4 + i) * 260 + colc] = f2bf(fast_tanh(acc[m][n][i] + b1v_));
      }
    }
    __syncthreads();
    const int r = t >> 3, sg = (t & 7) * 32;
    #pragma unroll
    for (int j = 0; j < 4; ++j)
      *(uint4*)(hreg + (size_t)(row0 + p * 64 + r) * 512 + colb + sg + j * 8) =
          *(const uint4*)(hp + r * 260 + sg + j * 8);
    __syncthreads();
  }
}

// ====== kbc1: ns2 = s2@[A2]ᵀ + h@WBᵀ + bias   (N=256, in-place over h0) ======
__global__ __launch_bounds__(512, 4) void kbc1(
    const float* __restrict__ s2,
    const unsigned short* __restrict__ h0s, const unsigned short* __restrict__ h1s,
    const unsigned short* __restrict__ wbf, const float* __restrict__ bias384,
    float* __restrict__ ns2)
{
  __shared__ unsigned short At[2][128 * ALD];
  __shared__ unsigned short Bt[2][256 * BLD];
  const int t = threadIdx.x, wc = t >> 6, lid = t & 63;
  const int lr = lid & 15, lg = lid >> 4;
  const int wm = wc >> 2, wn = wc & 3;
  const int row0 = blockIdx.x * 128;
  const int ar = t >> 2, ac = (t & 3) * 8;

  float4 a0, a1; uint4 av, b0, b1;
  auto loadA = [&](int ks) {
    if (ks < 8) {
      const float* q = s2 + (size_t)(row0 + ar) * 256 + ks * 32 + ac;
      a0 = *(const float4*)q; a1 = *(const float4*)(q + 4);
    } else {
      const int hk = (ks - 8) * 32;
      const unsigned short* reg = (hk < 512) ? h0s : h1s;
      av = *(const uint4*)(reg + (size_t)(row0 + ar) * 512 + (hk & 511) + ac);
    }
  };
  auto writeA = [&](int buf, bool isf) {
    if (isf) {
      uint4 h;
      h.x = cvtpk(a0.x, a0.y); h.y = cvtpk(a0.z, a0.w);
      h.z = cvtpk(a1.x, a1.y); h.w = cvtpk(a1.z, a1.w);
      *(uint4*)&At[buf][ar * ALD + ac] = h;
    } else {
      *(uint4*)&At[buf][ar * ALD + ac] = av;
    }
  };
  auto loadB = [&](int ks) {
    const size_t base = (ks < 8) ? (OFF_KBSP + (size_t)ks * 12288)
                                 : (OFF_KBHP + (size_t)(ks - 8) * 12288);
    const unsigned short* s = wbf + base + t * 8;
    b0 = *(const uint4*)s; b1 = *(const uint4*)(s + 4096);
  };
  auto writeB = [&](int buf) {
    *(uint4*)&Bt[buf][ar * BLD + ac] = b0;
    *(uint4*)&Bt[buf][(ar + 128) * BLD + ac] = b1;
  };

  f32x4 acc[4][4] = {};
  loadA(0); loadB(0); writeA(0, true); writeB(0);
  __syncthreads();
  for (int ks = 0; ks < 40; ++ks) {
    const int cur = ks & 1;
    if (ks < 39) { loadA(ks + 1); loadB(ks + 1); }
    bf16x8 a[4];
    #pragma unroll
    for (int m = 0; m < 4; ++m)
      a[m] = *(const bf16x8*)&At[cur][(wm * 64 + m * 16 + lr) * ALD + lg * 8];
    #pragma unroll
    for (int n = 0; n < 4; ++n) {
      bf16x8 b = *(const bf16x8*)&Bt[cur][(wn * 64 + n * 16 + lr) * BLD + lg * 8];
      #pragma unroll
      for (int m = 0; m < 4; ++m) MFMA16(acc[m][n], a[m], b);
    }
    if (ks < 39) { writeA(cur ^ 1, ks + 1 < 8); writeB(cur ^ 1); }
    __syncthreads();
  }
  #pragma unroll
  for (int n = 0; n < 4; ++n) {
    const int col = wn * 64 + n * 16 + lr;
    const float bv = bias384[col];
    #pragma unroll
    for (int m = 0; m < 4; ++m)
      #pragma unroll
      for (int i = 0; i < 4; ++i)
        ns2[(size_t)(row0 + wm * 64 + m * 16 + lg * 4 + i) * 256 + col] = acc[m][n][i] + bv;
  }
}

// ========= kbc2: y = s2@[C2]ᵀ + h@WDᵀ + bias   (N=128, over v-region) =========
__global__ __launch_bounds__(512, 4) void kbc2(
    const float* __restrict__ s2,
    const unsigned short* __restrict__ h0s, const unsigned short* __restrict__ h1s,
    const unsigned short* __restrict__ wbf, const float* __restrict__ bias384,
    float* __restrict__ y)
{
  __shared__ unsigned short At[2][128 * ALD];
  __shared__ unsigned short Bt[2][128 * BLD];   // 10240 B each
  const int t = threadIdx.x, wc = t >> 6, lid = t & 63;
  const int lr = lid & 15, lg = lid >> 4;
  const int wm = wc >> 2, wn = wc & 3;
  const int row0 = blockIdx.x * 128;
  const int ar = t >> 2, ac = (t & 3) * 8;

  float4 a0, a1; uint4 av, b0;
  auto loadA = [&](int ks) {
    if (ks < 8) {
      const float* q = s2 + (size_t)(row0 + ar) * 256 + ks * 32 + ac;
      a0 = *(const float4*)q; a1 = *(const float4*)(q + 4);
    } else {
      const int hk = (ks - 8) * 32;
      const unsigned short* reg = (hk < 512) ? h0s : h1s;
      av = *(const uint4*)(reg + (size_t)(row0 + ar) * 512 + (hk & 511) + ac);
    }
  };
  auto writeA = [&](int buf, bool isf) {
    if (isf) {
      uint4 h;
      h.x = cvtpk(a0.x, a0.y); h.y = cvtpk(a0.z, a0.w);
      h.z = cvtpk(a1.x, a1.y); h.w = cvtpk(a1.z, a1.w);
      *(uint4*)&At[buf][ar * ALD + ac] = h;
    } else {
      *(uint4*)&At[buf][ar * ALD + ac] = av;
    }
  };
  auto loadB = [&](int ks) {   // rows 256..383 of each packed slice
    const size_t base = (ks < 8) ? (OFF_KBSP + (size_t)ks * 12288)
                                 : (OFF_KBHP + (size_t)(ks - 8) * 12288);
    b0 = *(const uint4*)(wbf + base + 8192 + t * 8);
  };
  auto writeB = [&](int buf) { *(uint4*)&Bt[buf][ar * BLD + ac] = b0; };

  f32x4 acc[4][2] = {};
  loadA(0); loadB(0); writeA(0, true); writeB(0);
  __syncthreads();
  for (int ks = 0; ks < 40; ++ks) {
    const int cur = ks & 1;
    if (ks < 39) { loadA(ks + 1); loadB(ks + 1); }
    bf16x8 a[4];
    #pragma unroll
    for (int m = 0; m < 4; ++m)
      a[m] = *(const bf16x8*)&At[cur][(wm * 64 + m * 16 + lr) * ALD + lg * 8];
    #pragma unroll
    for (int n = 0; n < 2; ++n) {
      bf16x8 b = *(const bf16x8*)&Bt[cur][(wn * 32 + n * 16 + lr) * BLD + lg * 8];
      #pragma unroll
      for (int m = 0; m < 4; ++m) MFMA16(acc[m][n], a[m], b);
    }
    if (ks < 39) { writeA(cur ^ 1, ks + 1 < 8); writeB(cur ^ 1); }
    __syncthreads();
  }
  #pragma unroll
  for (int n = 0; n < 2; ++n) {
    const int col = wn * 32 + n * 16 + lr;
    const float bv = bias384[256 + col];
    #pragma unroll
    for (int m = 0; m < 4; ++m)
      #pragma unroll
      for (int i = 0; i < 4; ++i)
        y[(size_t)(row0 + wm * 64 + m * 16 + lg * 4 + i) * 128 + col] = acc[m][n][i] + bv;
  }
}

extern "C" void kernel_launch(void* const* d_in, const int* in_sizes, int n_in,
                              void* d_out, int out_size, void* d_ws, size_t ws_size,
                              hipStream_t stream) {
  const float* s1 = (const float*)d_in[0];
  const float* s2 = (const float*)d_in[1];
  const float* u  = (const float*)d_in[2];
  PP p;
  p.A1 = (const float*)d_in[3];
  p.B1 = (const float*)d_in[4];
  p.C1 = (const float*)d_in[5];
  p.D1 = (const float*)d_in[6];
  p.A2 = (const float*)d_in[7];
  p.B2 = (const float*)d_in[8];
  p.C2 = (const float*)d_in[9];
  p.D2 = (const float*)d_in[10];
  p.W1 = (const float*)d_in[11];
  p.W2 = (const float*)d_in[13];
  p.b2 = (const float*)d_in[14];
  const float* b1 = (const float*)d_in[12];

  unsigned short* wbf = (unsigned short*)d_ws;
  float* bias384 = (float*)((char*)d_ws + OFF_BIAS_BYTES);
  float* out = (float*)d_out;
  float* out2 = out + (size_t)NB * 256;     // ns2 region (64MB)
  float* outy = out + (size_t)NB * 512;     // y region (32MB)
  // region reuse: v in y-region; h = [ns2-region | ns1-region]
  unsigned short* vtmp = (unsigned short*)outy;   // [65536][256] bf16
  unsigned short* h0   = (unsigned short*)out2;   // h cols 0..511
  unsigned short* h1   = (unsigned short*)out;    // h cols 512..1023

  prep<<<dim3(466), dim3(256), 0, stream>>>(p, wbf, bias384);
  // v = s1@C1ᵀ + u@D1ᵀ  -> vtmp (bf16)
  k256<<<dim3(NB / 128), dim3(512), 0, stream>>>(s1, u, wbf, OFF_KAVP, nullptr, vtmp);
  // h = tanh(v@W1ᵀ + b1) -> h0|h1
  kbh<<<dim3((NB / 128) * 4), dim3(512), 0, stream>>>(vtmp, wbf, b1, h0, h1);
  // y = s2@C2ᵀ + h@WDᵀ + bias  (overwrites v-region; v already consumed)
  kbc2<<<dim3(NB / 128), dim3(512), 0, stream>>>(s2, h0, h1, wbf, bias384, outy);
  // ns2 = s2@A2ᵀ + h@WBᵀ + bias  (in-place over h0 rows)
  kbc1<<<dim3(NB / 128), dim3(512), 0, stream>>>(s2, h0, h1, wbf, bias384, out2);
  // ns1 = s1@A1ᵀ + u@B1ᵀ -> out (overwrites h1, already consumed)
  k256<<<dim3(NB / 128), dim3(512), 0, stream>>>(s1, u, wbf, OFF_KANP, out, nullptr);
}